// Round 1
// baseline (2059.706 us; speedup 1.0000x reference)
//
#include <hip/hip_runtime.h>

#define NS 32768
#define NLEV 4
#define NF 512
#define HID 512
#define VQD 64
#define CBS 4096

typedef __attribute__((ext_vector_type(8))) short bf16x8;
typedef __attribute__((ext_vector_type(4))) float f32x4;

__device__ inline unsigned short f2bf(float f) {
    unsigned int u = __float_as_uint(f);
    unsigned int r = (u + 0x7FFFu + ((u >> 16) & 1u)) >> 16;
    return (unsigned short)r;
}

// ---------------- prep kernels ----------------

// dst[b][c][r] = bf16(src[b][r][c])
__global__ void transpose_bf16(const float* __restrict__ src, unsigned short* __restrict__ dst,
                               int B, int R, int C) {
    long i = (long)blockIdx.x * 256 + threadIdx.x;
    long total = (long)B * R * C;
    if (i >= total) return;
    int r = (int)(i % R);
    long t = i / R;
    int c = (int)(t % C);
    int b = (int)(t / C);
    dst[i] = f2bf(src[((long)b * R + r) * C + c]);
}

__global__ void cb_prep(const float* __restrict__ cb, unsigned short* __restrict__ cbb,
                        float* __restrict__ cbn) {
    int i = blockIdx.x * 256 + threadIdx.x;  // l*CBS + n
    if (i >= NLEV * CBS) return;
    const float* row = cb + (long)i * VQD;
    float s = 0.f;
    for (int k = 0; k < VQD; k++) {
        float v = row[k];
        s += v * v;
        cbb[(long)i * VQD + k] = f2bf(v);
    }
    cbn[i] = s;
}

// ---------------- generic 64x64-tile MFMA GEMM ----------------
// C[m][n] = act( sum_k A[m][k] * Bt[n][k] + bias[n] )
// OUT_MODE: 0 = write bf16 C; 1 = write f32 C and bf16 C; 2 = fused MSE vs Xref (no C write)
template <int A_F32, int RELU, int OUT_MODE>
__global__ __launch_bounds__(256) void gemm64(
    const void* __restrict__ Ap, long astride, const unsigned short* __restrict__ Bt,
    const float* __restrict__ bias, unsigned short* __restrict__ Cb, float* __restrict__ Cf,
    const float* __restrict__ Xref, long xstride, float* __restrict__ accum, int Ntot, int K) {
    __shared__ __align__(16) short As[64 * 32];
    __shared__ __align__(16) short Bs[64 * 32];
    const int tid = threadIdx.x;
    const int m0 = blockIdx.x * 64;
    const int n0 = blockIdx.y * 64;
    const int wave = tid >> 6, lane = tid & 63, quad = lane >> 4, lr = lane & 15;
    const int srow = tid >> 2, sc8 = (tid & 3) * 8;

    f32x4 acc[4] = {{0.f, 0.f, 0.f, 0.f}, {0.f, 0.f, 0.f, 0.f}, {0.f, 0.f, 0.f, 0.f}, {0.f, 0.f, 0.f, 0.f}};

    for (int k0 = 0; k0 < K; k0 += 32) {
        if (A_F32) {
            const float* ap = (const float*)Ap + (long)(m0 + srow) * astride + k0 + sc8;
            float4 f0 = *(const float4*)ap;
            float4 f1 = *(const float4*)(ap + 4);
            short t[8];
            t[0] = (short)f2bf(f0.x); t[1] = (short)f2bf(f0.y); t[2] = (short)f2bf(f0.z); t[3] = (short)f2bf(f0.w);
            t[4] = (short)f2bf(f1.x); t[5] = (short)f2bf(f1.y); t[6] = (short)f2bf(f1.z); t[7] = (short)f2bf(f1.w);
            *(int4*)&As[srow * 32 + sc8] = *(const int4*)t;
        } else {
            const unsigned short* ap = (const unsigned short*)Ap + (long)(m0 + srow) * astride + k0 + sc8;
            *(int4*)&As[srow * 32 + sc8] = *(const int4*)ap;
        }
        {
            const unsigned short* bp = Bt + (long)(n0 + srow) * K + k0 + sc8;
            *(int4*)&Bs[srow * 32 + sc8] = *(const int4*)bp;
        }
        __syncthreads();
        bf16x8 a = *(const bf16x8*)&As[(wave * 16 + lr) * 32 + quad * 8];
#pragma unroll
        for (int nt = 0; nt < 4; nt++) {
            bf16x8 b = *(const bf16x8*)&Bs[(nt * 16 + lr) * 32 + quad * 8];
            acc[nt] = __builtin_amdgcn_mfma_f32_16x16x32_bf16(a, b, acc[nt], 0, 0, 0);
        }
        __syncthreads();
    }

    float lsum = 0.f;
#pragma unroll
    for (int nt = 0; nt < 4; nt++) {
        int col = n0 + nt * 16 + lr;
        float bv = bias[col];
#pragma unroll
        for (int r = 0; r < 4; r++) {
            int row = m0 + wave * 16 + quad * 4 + r;
            float v = acc[nt][r] + bv;
            if (RELU) v = v > 0.f ? v : 0.f;
            if (OUT_MODE == 0) {
                Cb[(long)row * Ntot + col] = f2bf(v);
            } else if (OUT_MODE == 1) {
                Cf[(long)row * Ntot + col] = v;
                Cb[(long)row * Ntot + col] = f2bf(v);
            } else {
                float d = v - Xref[(long)row * xstride + col];
                lsum += d * d;
            }
        }
    }
    if (OUT_MODE == 2) {
#pragma unroll
        for (int off = 32; off; off >>= 1) lsum += __shfl_down(lsum, off, 64);
        if (lane == 0) atomicAdd(accum, lsum);
    }
}

// ---------------- VQ distance + argmin ----------------
// d[m][n] = cbn[n] - 2 * z[m].c[n]  (||z||^2 omitted: constant per row)
__global__ __launch_bounds__(256) void vq_argmin(const unsigned short* __restrict__ Zb,
                                                 const unsigned short* __restrict__ cbb,
                                                 const float* __restrict__ cbn,
                                                 int* __restrict__ idxo) {
    __shared__ __align__(16) short Zs[64 * 64];
    __shared__ __align__(16) short Cs[64 * 64];
    const int tid = threadIdx.x;
    const int m0 = blockIdx.x * 64;
    const int wave = tid >> 6, lane = tid & 63, quad = lane >> 4, lr = lane & 15;
    {
        int row = tid >> 2, c = (tid & 3) * 16;
        const int4* src = (const int4*)(Zb + (long)(m0 + row) * VQD + c);
        int4* dst = (int4*)&Zs[row * 64 + c];
        dst[0] = src[0];
        dst[1] = src[1];
    }
    __syncthreads();
    bf16x8 a0 = *(const bf16x8*)&Zs[(wave * 16 + lr) * 64 + quad * 8];
    bf16x8 a1 = *(const bf16x8*)&Zs[(wave * 16 + lr) * 64 + 32 + quad * 8];

    float minv[4] = {1e30f, 1e30f, 1e30f, 1e30f};
    int mini[4] = {0, 0, 0, 0};

    for (int nb = 0; nb < CBS; nb += 64) {
        __syncthreads();
        {
            int row = tid >> 2, c = (tid & 3) * 16;
            const int4* src = (const int4*)(cbb + (long)(nb + row) * VQD + c);
            int4* dst = (int4*)&Cs[row * 64 + c];
            dst[0] = src[0];
            dst[1] = src[1];
        }
        __syncthreads();
#pragma unroll
        for (int nt = 0; nt < 4; nt++) {
            bf16x8 b0 = *(const bf16x8*)&Cs[(nt * 16 + lr) * 64 + quad * 8];
            bf16x8 b1 = *(const bf16x8*)&Cs[(nt * 16 + lr) * 64 + 32 + quad * 8];
            f32x4 acc = {0.f, 0.f, 0.f, 0.f};
            acc = __builtin_amdgcn_mfma_f32_16x16x32_bf16(a0, b0, acc, 0, 0, 0);
            acc = __builtin_amdgcn_mfma_f32_16x16x32_bf16(a1, b1, acc, 0, 0, 0);
            int n = nb + nt * 16 + lr;
            float cn = cbn[n];
#pragma unroll
            for (int r = 0; r < 4; r++) {
                float d = cn - 2.0f * acc[r];
                if (d < minv[r] || (d == minv[r] && n < mini[r])) {
                    minv[r] = d;
                    mini[r] = n;
                }
            }
        }
    }
#pragma unroll
    for (int r = 0; r < 4; r++) {
        float v = minv[r];
        int ix = mini[r];
#pragma unroll
        for (int off = 8; off; off >>= 1) {
            float ov = __shfl_xor(v, off, 64);
            int oi = __shfl_xor(ix, off, 64);
            if (ov < v || (ov == v && oi < ix)) {
                v = ov;
                ix = oi;
            }
        }
        if (lr == 0) idxo[m0 + wave * 16 + quad * 4 + r] = ix;
    }
}

// ---------------- gather q (+ commit SSE on last level) ----------------
template <int DO_COMMIT>
__global__ __launch_bounds__(256) void gather_q(const int* __restrict__ idx,
                                                const unsigned short* __restrict__ cbb,
                                                const float* __restrict__ cbf,
                                                const float* __restrict__ zf,
                                                unsigned short* __restrict__ qb,
                                                float* __restrict__ accum) {
    int m = blockIdx.x * 256 + threadIdx.x;
    int id = idx[m];
    const int4* src = (const int4*)(cbb + (long)id * VQD);
    int4* dst = (int4*)(qb + (long)m * VQD);
#pragma unroll
    for (int j = 0; j < 8; j++) dst[j] = src[j];
    if (DO_COMMIT) {
        const float* c = cbf + (long)id * VQD;
        const float* z = zf + (long)m * VQD;
        float s = 0.f;
#pragma unroll
        for (int k = 0; k < VQD; k++) {
            float d = c[k] - z[k];
            s += d * d;
        }
        int lane = threadIdx.x & 63;
#pragma unroll
        for (int off = 32; off; off >>= 1) s += __shfl_down(s, off, 64);
        if (lane == 0) atomicAdd(accum, s);
    }
}

__global__ void finalize_k(const float* __restrict__ accum, float* __restrict__ out) {
    out[0] = accum[0] / ((float)NS * NF * NLEV);
    out[1] = 0.25f * accum[1] / ((float)NS * VQD * NLEV);
}

// ---------------- launch ----------------
extern "C" void kernel_launch(void* const* d_in, const int* in_sizes, int n_in, void* d_out,
                              int out_size, void* d_ws, size_t ws_size, hipStream_t stream) {
    const float* x = (const float*)d_in[0];
    const float* enc_w1 = (const float*)d_in[1];
    const float* enc_b1 = (const float*)d_in[2];
    const float* enc_w2 = (const float*)d_in[3];
    const float* enc_b2 = (const float*)d_in[4];
    const float* dec_w1 = (const float*)d_in[5];
    const float* dec_b1 = (const float*)d_in[6];
    const float* dec_w2 = (const float*)d_in[7];
    const float* dec_b2 = (const float*)d_in[8];
    const float* cb = (const float*)d_in[9];

    char* ws = (char*)d_ws;
    size_t o = 0;
    float* accum = (float*)(ws + o); o += 256;
    unsigned short* enc_w1t = (unsigned short*)(ws + o); o += (size_t)NLEV * HID * NF * 2;    // [l][n=512][k=512]
    unsigned short* enc_w2t = (unsigned short*)(ws + o); o += (size_t)NLEV * VQD * HID * 2;   // [l][n=64][k=512]
    unsigned short* dec_w1t = (unsigned short*)(ws + o); o += (size_t)NLEV * HID * VQD * 2;   // [l][n=512][k=64]
    unsigned short* dec_w2t = (unsigned short*)(ws + o); o += (size_t)NLEV * NF * HID * 2;    // [l][n=512][k=512]
    unsigned short* cbb = (unsigned short*)(ws + o); o += (size_t)NLEV * CBS * VQD * 2;
    float* cbn = (float*)(ws + o); o += (size_t)NLEV * CBS * 4;
    unsigned short* hb = (unsigned short*)(ws + o); o += (size_t)NS * HID * 2;
    float* zf = (float*)(ws + o); o += (size_t)NS * VQD * 4;
    unsigned short* zb = (unsigned short*)(ws + o); o += (size_t)NS * VQD * 2;
    unsigned short* qb = (unsigned short*)(ws + o); o += (size_t)NS * VQD * 2;
    unsigned short* h2b = (unsigned short*)(ws + o); o += (size_t)NS * HID * 2;
    int* idxp = (int*)(ws + o); o += (size_t)NS * 4;

    hipMemsetAsync(accum, 0, 8, stream);

    transpose_bf16<<<(NLEV * NF * HID + 255) / 256, 256, 0, stream>>>(enc_w1, enc_w1t, NLEV, NF, HID);
    transpose_bf16<<<(NLEV * HID * VQD + 255) / 256, 256, 0, stream>>>(enc_w2, enc_w2t, NLEV, HID, VQD);
    transpose_bf16<<<(NLEV * VQD * HID + 255) / 256, 256, 0, stream>>>(dec_w1, dec_w1t, NLEV, VQD, HID);
    transpose_bf16<<<(NLEV * HID * NF + 255) / 256, 256, 0, stream>>>(dec_w2, dec_w2t, NLEV, HID, NF);
    cb_prep<<<(NLEV * CBS + 255) / 256, 256, 0, stream>>>(cb, cbb, cbn);

    for (int l = 0; l < NLEV; l++) {
        dim3 gBig(NS / 64, HID / 64);
        // enc1: h = relu(x_l @ enc_w1 + b1)
        gemm64<1, 1, 0><<<gBig, 256, 0, stream>>>(
            x + (long)l * NF, (long)NLEV * NF, enc_w1t + (long)l * HID * NF, enc_b1 + (long)l * HID,
            hb, nullptr, nullptr, 0, nullptr, HID, NF);
        // enc2: z = h @ enc_w2 + b2   (write f32 + bf16)
        dim3 gZ(NS / 64, VQD / 64);
        gemm64<0, 0, 1><<<gZ, 256, 0, stream>>>(
            hb, HID, enc_w2t + (long)l * VQD * HID, enc_b2 + (long)l * VQD,
            zb, zf, nullptr, 0, nullptr, VQD, HID);
        // argmin over codebook
        vq_argmin<<<NS / 64, 256, 0, stream>>>(zb, cbb + (long)l * CBS * VQD, cbn + (long)l * CBS, idxp);
        // gather q; commit SSE only for last level
        if (l == NLEV - 1)
            gather_q<1><<<NS / 256, 256, 0, stream>>>(idxp, cbb + (long)l * CBS * VQD,
                                                      cb + (long)l * CBS * VQD, zf, qb, accum + 1);
        else
            gather_q<0><<<NS / 256, 256, 0, stream>>>(idxp, cbb + (long)l * CBS * VQD,
                                                      nullptr, nullptr, qb, nullptr);
        // dec1: h2 = relu(q @ dec_w1 + b1d)
        gemm64<0, 1, 0><<<gBig, 256, 0, stream>>>(
            qb, VQD, dec_w1t + (long)l * HID * VQD, dec_b1 + (long)l * HID,
            h2b, nullptr, nullptr, 0, nullptr, HID, VQD);
        // dec2 + fused MSE: x_hat = h2 @ dec_w2 + b2d; accumulate sum((x_hat - x_l)^2)
        gemm64<0, 0, 2><<<gBig, 256, 0, stream>>>(
            h2b, HID, dec_w2t + (long)l * NF * HID, dec_b2 + (long)l * NF,
            nullptr, nullptr, x + (long)l * NF, (long)NLEV * NF, accum, NF, HID);
    }
    finalize_k<<<1, 1, 0, stream>>>(accum, (float*)d_out);
}

// Round 2
// 1287.121 us; speedup vs baseline: 1.6002x; 1.6002x over previous
//
#include <hip/hip_runtime.h>

#define NS 32768
#define NLEV 4
#define NF 512
#define HID 512
#define VQD 64
#define CBS 4096

typedef __attribute__((ext_vector_type(8))) short bf16x8;
typedef __attribute__((ext_vector_type(4))) float f32x4;

__device__ inline unsigned short f2bf(float f) {
    unsigned int u = __float_as_uint(f);
    unsigned int r = (u + 0x7FFFu + ((u >> 16) & 1u)) >> 16;
    return (unsigned short)r;
}

// async global->LDS, 16B per lane; lds base must be wave-uniform
__device__ __forceinline__ void gl16(const void* g, void* l) {
    __builtin_amdgcn_global_load_lds(
        (const __attribute__((address_space(1))) unsigned int*)g,
        (__attribute__((address_space(3))) unsigned int*)l, 16, 0, 0);
}

// ---------------- prep kernels ----------------

// dst[b][c][r] = bf16(src[b][r][c])
__global__ void transpose_bf16(const float* __restrict__ src, unsigned short* __restrict__ dst,
                               int B, int R, int C) {
    long i = (long)blockIdx.x * 256 + threadIdx.x;
    long total = (long)B * R * C;
    if (i >= total) return;
    int r = (int)(i % R);
    long t = i / R;
    int c = (int)(t % C);
    int b = (int)(t / C);
    dst[i] = f2bf(src[((long)b * R + r) * C + c]);
}

__global__ void cb_prep(const float* __restrict__ cb, unsigned short* __restrict__ cbb,
                        float* __restrict__ cbn) {
    int i = blockIdx.x * 256 + threadIdx.x;  // l*CBS + n
    if (i >= NLEV * CBS) return;
    const float* row = cb + (long)i * VQD;
    float s = 0.f;
    for (int k = 0; k < VQD; k++) {
        float v = row[k];
        s += v * v;
        cbb[(long)i * VQD + k] = f2bf(v);
    }
    cbn[i] = s;
}

// per-level x slice fp32 -> bf16, layout [n][f]
__global__ void xconv(const float* __restrict__ x, unsigned short* __restrict__ xbl, int l) {
    int i = blockIdx.x * 256 + threadIdx.x;  // one per 8 elements
    int n = i >> 6;
    int f8 = (i & 63) * 8;
    const float* src = x + ((long)n * NLEV + l) * NF + f8;
    float4 f0 = *(const float4*)src;
    float4 f1 = *(const float4*)(src + 4);
    short t[8];
    t[0] = (short)f2bf(f0.x); t[1] = (short)f2bf(f0.y); t[2] = (short)f2bf(f0.z); t[3] = (short)f2bf(f0.w);
    t[4] = (short)f2bf(f1.x); t[5] = (short)f2bf(f1.y); t[6] = (short)f2bf(f1.z); t[7] = (short)f2bf(f1.w);
    *(int4*)(xbl + (long)n * NF + f8) = *(const int4*)t;
}

// ---------------- 128x128-tile MFMA GEMM (m97 structure) ----------------
// C[m][n] = act( sum_k A[m][k] * Bt[n][k] + bias[n] )
// NT: n-tiles of 16 per wave (4 -> BN=128, 2 -> BN=64)
// OUT_MODE: 0 = bf16 C; 1 = f32 C + bf16 C; 2 = fused MSE vs Xref (no C write)
// GATHER: A row = codebook[idx[m]] (astride ignored, row length = K)
template <int NT, int RELU, int OUT_MODE, int GATHER>
__global__ __launch_bounds__(256) void gemm128(
    const unsigned short* __restrict__ Ab, long astride, const int* __restrict__ idx,
    const unsigned short* __restrict__ Bt, const float* __restrict__ bias,
    unsigned short* __restrict__ Cb, float* __restrict__ Cf,
    const float* __restrict__ Xref, long xstride, float* __restrict__ accum, int Ntot, int K) {
    constexpr int BN = NT * 32;
    __shared__ __align__(16) short As[128 * 32];
    __shared__ __align__(16) short Bs[BN * 32];
    const int tid = threadIdx.x;
    const int m0 = blockIdx.x * 128;
    const int n0 = blockIdx.y * BN;
    const int wave = tid >> 6, lane = tid & 63, quad = lane >> 4, lr = lane & 15;
    const int wm = wave >> 1, wn = wave & 1;
    const int lrow = lane >> 2;       // 0..15
    const int lcol = (lane & 3) * 8;  // 0,8,16,24

    f32x4 acc[4][NT];
#pragma unroll
    for (int i = 0; i < 4; i++)
#pragma unroll
        for (int j = 0; j < NT; j++) acc[i][j] = (f32x4){0.f, 0.f, 0.f, 0.f};

    for (int k0 = 0; k0 < K; k0 += 32) {
        // A staging: 2 instrs, rows [i*64 + wave*16, +16)
        if (GATHER) {
            int r0 = m0 + wave * 16 + lrow;
            gl16(Ab + (long)idx[r0] * K + k0 + lcol, &As[(wave * 16) * 32]);
            gl16(Ab + (long)idx[r0 + 64] * K + k0 + lcol, &As[(64 + wave * 16) * 32]);
        } else {
            const unsigned short* ga = Ab + (long)(m0 + wave * 16 + lrow) * astride + k0 + lcol;
            gl16(ga, &As[(wave * 16) * 32]);
            gl16(ga + 64 * astride, &As[(64 + wave * 16) * 32]);
        }
        // B staging
        const unsigned short* gb = Bt + (long)(n0 + wave * 16 + lrow) * K + k0 + lcol;
        gl16(gb, &Bs[(wave * 16) * 32]);
        if (NT == 4) gl16(gb + 64 * (long)K, &Bs[(64 + wave * 16) * 32]);
        __syncthreads();

        bf16x8 af[4], bf[NT];
#pragma unroll
        for (int mt = 0; mt < 4; mt++)
            af[mt] = *(const bf16x8*)&As[(wm * 64 + mt * 16 + lr) * 32 + quad * 8];
#pragma unroll
        for (int nt = 0; nt < NT; nt++)
            bf[nt] = *(const bf16x8*)&Bs[(wn * NT * 16 + nt * 16 + lr) * 32 + quad * 8];
#pragma unroll
        for (int mt = 0; mt < 4; mt++)
#pragma unroll
            for (int nt = 0; nt < NT; nt++)
                acc[mt][nt] = __builtin_amdgcn_mfma_f32_16x16x32_bf16(af[mt], bf[nt], acc[mt][nt], 0, 0, 0);
        __syncthreads();
    }

    float lsum = 0.f;
#pragma unroll
    for (int nt = 0; nt < NT; nt++) {
        int col = n0 + wn * NT * 16 + nt * 16 + lr;
        float bv = bias[col];
#pragma unroll
        for (int mt = 0; mt < 4; mt++) {
#pragma unroll
            for (int r = 0; r < 4; r++) {
                int row = m0 + wm * 64 + mt * 16 + quad * 4 + r;
                float v = acc[mt][nt][r] + bv;
                if (RELU) v = v > 0.f ? v : 0.f;
                if (OUT_MODE == 0) {
                    Cb[(long)row * Ntot + col] = f2bf(v);
                } else if (OUT_MODE == 1) {
                    Cf[(long)row * Ntot + col] = v;
                    Cb[(long)row * Ntot + col] = f2bf(v);
                } else {
                    float d = v - Xref[(long)row * xstride + col];
                    lsum += d * d;
                }
            }
        }
    }
    if (OUT_MODE == 2) {
#pragma unroll
        for (int off = 32; off; off >>= 1) lsum += __shfl_down(lsum, off, 64);
        if (lane == 0) atomicAdd(accum, lsum);
    }
}

// ---------------- VQ distance + argmin, 128-row tile ----------------
// d[m][n] = cbn[n] - 2 * z[m].c[n]  (||z||^2 constant per row, omitted)
// LDS panel layout [2][rows][32] to keep 64B rows (8-way max conflict)
__global__ __launch_bounds__(256) void vq_argmin(const unsigned short* __restrict__ Zb,
                                                 const unsigned short* __restrict__ cbb,
                                                 const float* __restrict__ cbn,
                                                 int* __restrict__ idxo) {
    __shared__ __align__(16) short Zs[2 * 128 * 32];
    __shared__ __align__(16) short Cs[2 * 64 * 32];
    const int tid = threadIdx.x;
    const int m0 = blockIdx.x * 128;
    const int wave = tid >> 6, lane = tid & 63, quad = lane >> 4, lr = lane & 15;
    const int lrow = lane >> 2, lcol = (lane & 3) * 8;

    // stage Z into [2][128][32] panels (once)
#pragma unroll
    for (int j = 0; j < 4; j++) {
        int f = tid * 4 + j;             // int4 index, 0..1023
        int p = f >> 9;                  // panel
        int rem = f & 511;
        int r = rem >> 2;
        int c = (rem & 3) * 8;
        ((int4*)Zs)[f] = *(const int4*)(Zb + (long)(m0 + r) * VQD + p * 32 + c);
    }
    __syncthreads();
    bf16x8 a[2][2];
#pragma unroll
    for (int h = 0; h < 2; h++)
#pragma unroll
        for (int p = 0; p < 2; p++)
            a[h][p] = *(const bf16x8*)&Zs[p * 4096 + (h * 64 + wave * 16 + lr) * 32 + quad * 8];

    float minv[2][4] = {{1e30f, 1e30f, 1e30f, 1e30f}, {1e30f, 1e30f, 1e30f, 1e30f}};
    int mini[2][4] = {{0, 0, 0, 0}, {0, 0, 0, 0}};

    for (int nb = 0; nb < CBS; nb += 64) {
        __syncthreads();
        // stage 64 codebook rows into [2][64][32] panels via global_load_lds
#pragma unroll
        for (int i = 0; i < 2; i++) {
            int s = i * 4 + wave;        // segment 0..7
            int p = s >> 2;
            int r0 = (s & 3) * 16;
            gl16(cbb + (long)(nb + r0 + lrow) * VQD + p * 32 + lcol, &Cs[s * 512]);
        }
        __syncthreads();
#pragma unroll
        for (int nt = 0; nt < 4; nt++) {
            bf16x8 b0 = *(const bf16x8*)&Cs[(nt * 16 + lr) * 32 + quad * 8];
            bf16x8 b1 = *(const bf16x8*)&Cs[2048 + (nt * 16 + lr) * 32 + quad * 8];
            int n = nb + nt * 16 + lr;
            float cn = cbn[n];
#pragma unroll
            for (int h = 0; h < 2; h++) {
                f32x4 acc = {0.f, 0.f, 0.f, 0.f};
                acc = __builtin_amdgcn_mfma_f32_16x16x32_bf16(a[h][0], b0, acc, 0, 0, 0);
                acc = __builtin_amdgcn_mfma_f32_16x16x32_bf16(a[h][1], b1, acc, 0, 0, 0);
#pragma unroll
                for (int r = 0; r < 4; r++) {
                    float d = cn - 2.0f * acc[r];
                    if (d < minv[h][r]) {
                        minv[h][r] = d;
                        mini[h][r] = n;
                    }
                }
            }
        }
    }
#pragma unroll
    for (int h = 0; h < 2; h++)
#pragma unroll
        for (int r = 0; r < 4; r++) {
            float v = minv[h][r];
            int ix = mini[h][r];
#pragma unroll
            for (int off = 8; off; off >>= 1) {
                float ov = __shfl_xor(v, off, 64);
                int oi = __shfl_xor(ix, off, 64);
                if (ov < v || (ov == v && oi < ix)) {
                    v = ov;
                    ix = oi;
                }
            }
            if (lr == 0) idxo[m0 + h * 64 + wave * 16 + quad * 4 + r] = ix;
        }
}

// ---------------- commit SSE (last level only) ----------------
__global__ __launch_bounds__(256) void commit_k(const int* __restrict__ idx,
                                                const float* __restrict__ cbf,
                                                const float* __restrict__ zf,
                                                float* __restrict__ accum) {
    int m = blockIdx.x * 256 + threadIdx.x;
    int id = idx[m];
    const float* c = cbf + (long)id * VQD;
    const float* z = zf + (long)m * VQD;
    float s = 0.f;
#pragma unroll
    for (int k = 0; k < VQD; k++) {
        float d = c[k] - z[k];
        s += d * d;
    }
    int lane = threadIdx.x & 63;
#pragma unroll
    for (int off = 32; off; off >>= 1) s += __shfl_down(s, off, 64);
    if (lane == 0) atomicAdd(accum, s);
}

__global__ void finalize_k(const float* __restrict__ accum, float* __restrict__ out) {
    out[0] = accum[0] / ((float)NS * NF * NLEV);
    out[1] = 0.25f * accum[1] / ((float)NS * VQD * NLEV);
}

// ---------------- launch ----------------
extern "C" void kernel_launch(void* const* d_in, const int* in_sizes, int n_in, void* d_out,
                              int out_size, void* d_ws, size_t ws_size, hipStream_t stream) {
    const float* x = (const float*)d_in[0];
    const float* enc_w1 = (const float*)d_in[1];
    const float* enc_b1 = (const float*)d_in[2];
    const float* enc_w2 = (const float*)d_in[3];
    const float* enc_b2 = (const float*)d_in[4];
    const float* dec_w1 = (const float*)d_in[5];
    const float* dec_b1 = (const float*)d_in[6];
    const float* dec_w2 = (const float*)d_in[7];
    const float* dec_b2 = (const float*)d_in[8];
    const float* cb = (const float*)d_in[9];

    char* ws = (char*)d_ws;
    size_t o = 0;
    float* accum = (float*)(ws + o); o += 256;
    unsigned short* enc_w1t = (unsigned short*)(ws + o); o += (size_t)NLEV * HID * NF * 2;   // [l][n][k]
    unsigned short* enc_w2t = (unsigned short*)(ws + o); o += (size_t)NLEV * VQD * HID * 2;
    unsigned short* dec_w1t = (unsigned short*)(ws + o); o += (size_t)NLEV * HID * VQD * 2;
    unsigned short* dec_w2t = (unsigned short*)(ws + o); o += (size_t)NLEV * NF * HID * 2;
    unsigned short* cbb = (unsigned short*)(ws + o); o += (size_t)NLEV * CBS * VQD * 2;
    float* cbn = (float*)(ws + o); o += (size_t)NLEV * CBS * 4;
    unsigned short* xbl = (unsigned short*)(ws + o); o += (size_t)NS * NF * 2;  // per-level bf16 x; reused as h2b
    unsigned short* hb = (unsigned short*)(ws + o); o += (size_t)NS * HID * 2;
    float* zf = (float*)(ws + o); o += (size_t)NS * VQD * 4;
    unsigned short* zb = (unsigned short*)(ws + o); o += (size_t)NS * VQD * 2;
    int* idxp = (int*)(ws + o); o += (size_t)NS * 4;
    unsigned short* h2b = xbl;  // alias: xbl dead after enc1, h2b live dec1->dec2

    hipMemsetAsync(accum, 0, 8, stream);

    transpose_bf16<<<(NLEV * NF * HID + 255) / 256, 256, 0, stream>>>(enc_w1, enc_w1t, NLEV, NF, HID);
    transpose_bf16<<<(NLEV * HID * VQD + 255) / 256, 256, 0, stream>>>(enc_w2, enc_w2t, NLEV, HID, VQD);
    transpose_bf16<<<(NLEV * VQD * HID + 255) / 256, 256, 0, stream>>>(dec_w1, dec_w1t, NLEV, VQD, HID);
    transpose_bf16<<<(NLEV * HID * NF + 255) / 256, 256, 0, stream>>>(dec_w2, dec_w2t, NLEV, HID, NF);
    cb_prep<<<(NLEV * CBS + 255) / 256, 256, 0, stream>>>(cb, cbb, cbn);

    for (int l = 0; l < NLEV; l++) {
        dim3 gBig(NS / 128, HID / 128);   // (256, 4)
        dim3 gZ(NS / 128, 1);
        // x slice -> bf16
        xconv<<<NS * (NF / 8) / 256, 256, 0, stream>>>(x, xbl, l);
        // enc1: h = relu(xb @ enc_w1 + b1)
        gemm128<4, 1, 0, 0><<<gBig, 256, 0, stream>>>(
            xbl, NF, nullptr, enc_w1t + (long)l * HID * NF, enc_b1 + (long)l * HID,
            hb, nullptr, nullptr, 0, nullptr, HID, NF);
        // enc2: z = h @ enc_w2 + b2 (f32 z only needed for commit on last level)
        if (l == NLEV - 1)
            gemm128<2, 0, 1, 0><<<gZ, 256, 0, stream>>>(
                hb, HID, nullptr, enc_w2t + (long)l * VQD * HID, enc_b2 + (long)l * VQD,
                zb, zf, nullptr, 0, nullptr, VQD, HID);
        else
            gemm128<2, 0, 0, 0><<<gZ, 256, 0, stream>>>(
                hb, HID, nullptr, enc_w2t + (long)l * VQD * HID, enc_b2 + (long)l * VQD,
                zb, nullptr, nullptr, 0, nullptr, VQD, HID);
        // argmin over codebook
        vq_argmin<<<NS / 128, 256, 0, stream>>>(zb, cbb + (long)l * CBS * VQD, cbn + (long)l * CBS, idxp);
        if (l == NLEV - 1)
            commit_k<<<NS / 256, 256, 0, stream>>>(idxp, cb + (long)l * CBS * VQD, zf, accum + 1);
        // dec1: h2 = relu(cb[idx] @ dec_w1 + b1d), gather fused into A staging
        gemm128<4, 1, 0, 1><<<gBig, 256, 0, stream>>>(
            cbb + (long)l * CBS * VQD, 0, idxp, dec_w1t + (long)l * HID * VQD, dec_b1 + (long)l * HID,
            h2b, nullptr, nullptr, 0, nullptr, HID, VQD);
        // dec2 + fused MSE
        gemm128<4, 0, 2, 0><<<gBig, 256, 0, stream>>>(
            h2b, HID, nullptr, dec_w2t + (long)l * NF * HID, dec_b2 + (long)l * NF,
            nullptr, nullptr, x + (long)l * NF, (long)NLEV * NF, accum, NF, HID);
    }
    finalize_k<<<1, 1, 0, stream>>>(accum, (float*)d_out);
}

// Round 3
// 931.502 us; speedup vs baseline: 2.2112x; 1.3818x over previous
//
#include <hip/hip_runtime.h>

#define NS 32768
#define NLEV 4
#define NF 512
#define HID 512
#define VQD 64
#define CBS 4096

typedef __attribute__((ext_vector_type(8))) short bf16x8;
typedef __attribute__((ext_vector_type(4))) float f32x4;

__device__ inline unsigned short f2bf(float f) {
    unsigned int u = __float_as_uint(f);
    unsigned int r = (u + 0x7FFFu + ((u >> 16) & 1u)) >> 16;
    return (unsigned short)r;
}

// async global->LDS, 16B per lane; lds base must be wave-uniform
__device__ __forceinline__ void gl16(const void* g, void* l) {
    __builtin_amdgcn_global_load_lds(
        (const __attribute__((address_space(1))) unsigned int*)g,
        (__attribute__((address_space(3))) unsigned int*)l, 16, 0, 0);
}

// ---------------- prep kernels ----------------

// all 4 weight transposes in one dispatch: dst[b][c][r] = bf16(src[b][r][c])
__global__ void transpose_all(const float* __restrict__ ew1, const float* __restrict__ ew2,
                              const float* __restrict__ dw1, const float* __restrict__ dw2,
                              unsigned short* __restrict__ ew1t, unsigned short* __restrict__ ew2t,
                              unsigned short* __restrict__ dw1t, unsigned short* __restrict__ dw2t) {
    long i = (long)blockIdx.x * 256 + threadIdx.x;
    const long s1 = (long)NLEV * NF * HID;
    const long s2 = (long)NLEV * HID * VQD;
    const long s3 = (long)NLEV * VQD * HID;
    const long s4 = (long)NLEV * HID * NF;
    const float* src;
    unsigned short* dst;
    int R, C;
    if (i < s1) { src = ew1; dst = ew1t; R = NF; C = HID; }
    else if (i < s1 + s2) { i -= s1; src = ew2; dst = ew2t; R = HID; C = VQD; }
    else if (i < s1 + s2 + s3) { i -= s1 + s2; src = dw1; dst = dw1t; R = VQD; C = HID; }
    else if (i < s1 + s2 + s3 + s4) { i -= s1 + s2 + s3; src = dw2; dst = dw2t; R = HID; C = NF; }
    else return;
    int r = (int)(i % R);
    long t = i / R;
    int c = (int)(t % C);
    int b = (int)(t / C);
    dst[i] = f2bf(src[((long)b * R + r) * C + c]);
}

__global__ void cb_prep(const float* __restrict__ cb, unsigned short* __restrict__ cbb,
                        float* __restrict__ cbn) {
    int i = blockIdx.x * 256 + threadIdx.x;  // l*CBS + n
    if (i >= NLEV * CBS) return;
    const float* row = cb + (long)i * VQD;
    float s = 0.f;
    for (int k = 0; k < VQD; k++) {
        float v = row[k];
        s += v * v;
        cbb[(long)i * VQD + k] = f2bf(v);
    }
    cbn[i] = s;
}

// all levels: x[n][l][f] fp32 -> xb[l][n][f] bf16
__global__ void xconv(const float* __restrict__ x, unsigned short* __restrict__ xb) {
    long i = (long)blockIdx.x * 256 + threadIdx.x;  // one per 8 elements
    int l = (int)(i / ((long)NS * (NF / 8)));
    long rem = i % ((long)NS * (NF / 8));
    int n = (int)(rem >> 6);
    int f8 = ((int)rem & 63) * 8;
    const float* src = x + ((long)n * NLEV + l) * NF + f8;
    float4 f0 = *(const float4*)src;
    float4 f1 = *(const float4*)(src + 4);
    short t[8];
    t[0] = (short)f2bf(f0.x); t[1] = (short)f2bf(f0.y); t[2] = (short)f2bf(f0.z); t[3] = (short)f2bf(f0.w);
    t[4] = (short)f2bf(f1.x); t[5] = (short)f2bf(f1.y); t[6] = (short)f2bf(f1.z); t[7] = (short)f2bf(f1.w);
    *(int4*)(xb + ((long)l * NS + n) * NF + f8) = *(const int4*)t;
}

// ---------------- 128x128-tile MFMA GEMM, level-batched over gridDim.z ----------------
// C[m][n] = act( sum_k A[m][k] * Bt[n][k] + bias[n] )
// NT: n-tiles of 16 per wave (4 -> BN=128, 2 -> BN=64)
// OUT_MODE: 0 = bf16 C; 1 = f32 C + bf16 C; 2 = fused MSE vs Xref (no C write)
// GATHER: A row = codebook[idx[m]] (astride ignored, row length = K)
template <int NT, int RELU, int OUT_MODE, int GATHER>
__global__ __launch_bounds__(256) void gemm128(
    const unsigned short* __restrict__ Ab, long astride, long abatch,
    const int* __restrict__ idx,
    const unsigned short* __restrict__ Bt, long bbatch,
    const float* __restrict__ bias, long biasbatch,
    unsigned short* __restrict__ Cb, float* __restrict__ Cf, long cbatch,
    const float* __restrict__ Xref, long xstride, long xbatch,
    float* __restrict__ accum, int Ntot, int K) {
    constexpr int BN = NT * 32;
    __shared__ __align__(16) short As[128 * 32];
    __shared__ __align__(16) short Bs[BN * 32];
    __shared__ float red[4];
    const int lvl = blockIdx.z;
    Ab += (long)lvl * abatch;
    Bt += (long)lvl * bbatch;
    bias += (long)lvl * biasbatch;
    if (OUT_MODE == 0 || OUT_MODE == 1) Cb += (long)lvl * cbatch;
    if (OUT_MODE == 1) Cf += (long)lvl * cbatch;
    if (OUT_MODE == 2) Xref += (long)lvl * xbatch;
    if (GATHER) idx += (long)lvl * NS;

    const int tid = threadIdx.x;
    const int m0 = blockIdx.x * 128;
    const int n0 = blockIdx.y * BN;
    const int wave = tid >> 6, lane = tid & 63, quad = lane >> 4, lr = lane & 15;
    const int wm = wave >> 1, wn = wave & 1;
    const int lrow = lane >> 2;       // 0..15
    const int lcol = (lane & 3) * 8;  // 0,8,16,24

    f32x4 acc[4][NT];
#pragma unroll
    for (int i = 0; i < 4; i++)
#pragma unroll
        for (int j = 0; j < NT; j++) acc[i][j] = (f32x4){0.f, 0.f, 0.f, 0.f};

    for (int k0 = 0; k0 < K; k0 += 32) {
        if (GATHER) {
            int r0 = m0 + wave * 16 + lrow;
            gl16(Ab + (long)idx[r0] * K + k0 + lcol, &As[(wave * 16) * 32]);
            gl16(Ab + (long)idx[r0 + 64] * K + k0 + lcol, &As[(64 + wave * 16) * 32]);
        } else {
            const unsigned short* ga = Ab + (long)(m0 + wave * 16 + lrow) * astride + k0 + lcol;
            gl16(ga, &As[(wave * 16) * 32]);
            gl16(ga + 64 * astride, &As[(64 + wave * 16) * 32]);
        }
        const unsigned short* gb = Bt + (long)(n0 + wave * 16 + lrow) * K + k0 + lcol;
        gl16(gb, &Bs[(wave * 16) * 32]);
        if (NT == 4) gl16(gb + 64 * (long)K, &Bs[(64 + wave * 16) * 32]);
        __syncthreads();

        bf16x8 af[4], bfr[NT];
#pragma unroll
        for (int mt = 0; mt < 4; mt++)
            af[mt] = *(const bf16x8*)&As[(wm * 64 + mt * 16 + lr) * 32 + quad * 8];
#pragma unroll
        for (int nt = 0; nt < NT; nt++)
            bfr[nt] = *(const bf16x8*)&Bs[(wn * NT * 16 + nt * 16 + lr) * 32 + quad * 8];
#pragma unroll
        for (int mt = 0; mt < 4; mt++)
#pragma unroll
            for (int nt = 0; nt < NT; nt++)
                acc[mt][nt] = __builtin_amdgcn_mfma_f32_16x16x32_bf16(af[mt], bfr[nt], acc[mt][nt], 0, 0, 0);
        __syncthreads();
    }

    float lsum = 0.f;
#pragma unroll
    for (int nt = 0; nt < NT; nt++) {
        int col = n0 + wn * NT * 16 + nt * 16 + lr;
        float bv = bias[col];
#pragma unroll
        for (int mt = 0; mt < 4; mt++) {
#pragma unroll
            for (int r = 0; r < 4; r++) {
                int row = m0 + wm * 64 + mt * 16 + quad * 4 + r;
                float v = acc[mt][nt][r] + bv;
                if (RELU) v = v > 0.f ? v : 0.f;
                if (OUT_MODE == 0) {
                    Cb[(long)row * Ntot + col] = f2bf(v);
                } else if (OUT_MODE == 1) {
                    Cf[(long)row * Ntot + col] = v;
                    Cb[(long)row * Ntot + col] = f2bf(v);
                } else {
                    float d = v - Xref[(long)row * xstride + col];
                    lsum += d * d;
                }
            }
        }
    }
    if (OUT_MODE == 2) {
#pragma unroll
        for (int off = 32; off; off >>= 1) lsum += __shfl_down(lsum, off, 64);
        if (lane == 0) red[wave] = lsum;
        __syncthreads();
        if (tid == 0) atomicAdd(accum, red[0] + red[1] + red[2] + red[3]);
    }
}

// ---------------- VQ distance + argmin, 128-row tile, level-batched over gridDim.y ----
// d[m][n] = cbn[n] - 2 * z[m].c[n]  (||z||^2 constant per row, omitted)
__global__ __launch_bounds__(256) void vq_argmin(const unsigned short* __restrict__ Zb,
                                                 const unsigned short* __restrict__ cbb,
                                                 const float* __restrict__ cbn,
                                                 int* __restrict__ idxo) {
    __shared__ __align__(16) short Zs[2 * 128 * 32];
    __shared__ __align__(16) short Cs[2 * 64 * 32];
    const int lvl = blockIdx.y;
    Zb += (long)lvl * NS * VQD;
    cbb += (long)lvl * CBS * VQD;
    cbn += (long)lvl * CBS;
    idxo += (long)lvl * NS;
    const int tid = threadIdx.x;
    const int m0 = blockIdx.x * 128;
    const int wave = tid >> 6, lane = tid & 63, quad = lane >> 4, lr = lane & 15;
    const int lrow = lane >> 2, lcol = (lane & 3) * 8;

#pragma unroll
    for (int j = 0; j < 4; j++) {
        int f = tid * 4 + j;  // int4 index, 0..1023
        int p = f >> 9;
        int rem = f & 511;
        int r = rem >> 2;
        int c = (rem & 3) * 8;
        ((int4*)Zs)[f] = *(const int4*)(Zb + (long)(m0 + r) * VQD + p * 32 + c);
    }
    __syncthreads();
    bf16x8 a[2][2];
#pragma unroll
    for (int h = 0; h < 2; h++)
#pragma unroll
        for (int p = 0; p < 2; p++)
            a[h][p] = *(const bf16x8*)&Zs[p * 4096 + (h * 64 + wave * 16 + lr) * 32 + quad * 8];

    float minv[2][4] = {{1e30f, 1e30f, 1e30f, 1e30f}, {1e30f, 1e30f, 1e30f, 1e30f}};
    int mini[2][4] = {{0, 0, 0, 0}, {0, 0, 0, 0}};

    for (int nb = 0; nb < CBS; nb += 64) {
        __syncthreads();
#pragma unroll
        for (int i = 0; i < 2; i++) {
            int s = i * 4 + wave;  // segment 0..7
            int p = s >> 2;
            int r0 = (s & 3) * 16;
            gl16(cbb + (long)(nb + r0 + lrow) * VQD + p * 32 + lcol, &Cs[s * 512]);
        }
        __syncthreads();
#pragma unroll
        for (int nt = 0; nt < 4; nt++) {
            bf16x8 b0 = *(const bf16x8*)&Cs[(nt * 16 + lr) * 32 + quad * 8];
            bf16x8 b1 = *(const bf16x8*)&Cs[2048 + (nt * 16 + lr) * 32 + quad * 8];
            int n = nb + nt * 16 + lr;
            float cn = cbn[n];
#pragma unroll
            for (int h = 0; h < 2; h++) {
                f32x4 acc = {0.f, 0.f, 0.f, 0.f};
                acc = __builtin_amdgcn_mfma_f32_16x16x32_bf16(a[h][0], b0, acc, 0, 0, 0);
                acc = __builtin_amdgcn_mfma_f32_16x16x32_bf16(a[h][1], b1, acc, 0, 0, 0);
#pragma unroll
                for (int r = 0; r < 4; r++) {
                    float d = cn - 2.0f * acc[r];
                    if (d < minv[h][r]) {
                        minv[h][r] = d;
                        mini[h][r] = n;
                    }
                }
            }
        }
    }
#pragma unroll
    for (int h = 0; h < 2; h++)
#pragma unroll
        for (int r = 0; r < 4; r++) {
            float v = minv[h][r];
            int ix = mini[h][r];
#pragma unroll
            for (int off = 8; off; off >>= 1) {
                float ov = __shfl_xor(v, off, 64);
                int oi = __shfl_xor(ix, off, 64);
                if (ov < v || (ov == v && oi < ix)) {
                    v = ov;
                    ix = oi;
                }
            }
            if (lr == 0) idxo[m0 + h * 64 + wave * 16 + quad * 4 + r] = ix;
        }
}

// ---------------- commit SSE (last level only) ----------------
__global__ __launch_bounds__(256) void commit_k(const int* __restrict__ idx,
                                                const float* __restrict__ cbf,
                                                const float* __restrict__ zf,
                                                float* __restrict__ accum) {
    int m = blockIdx.x * 256 + threadIdx.x;
    int id = idx[m];
    const float* c = cbf + (long)id * VQD;
    const float* z = zf + (long)m * VQD;
    float s = 0.f;
#pragma unroll
    for (int k = 0; k < VQD; k++) {
        float d = c[k] - z[k];
        s += d * d;
    }
    int lane = threadIdx.x & 63;
#pragma unroll
    for (int off = 32; off; off >>= 1) s += __shfl_down(s, off, 64);
    if (lane == 0) atomicAdd(accum, s);
}

__global__ void finalize_k(const float* __restrict__ accum, float* __restrict__ out) {
    out[0] = accum[0] / ((float)NS * NF * NLEV);
    out[1] = 0.25f * accum[1] / ((float)NS * VQD * NLEV);
}

// ---------------- launch ----------------
extern "C" void kernel_launch(void* const* d_in, const int* in_sizes, int n_in, void* d_out,
                              int out_size, void* d_ws, size_t ws_size, hipStream_t stream) {
    const float* x = (const float*)d_in[0];
    const float* enc_w1 = (const float*)d_in[1];
    const float* enc_b1 = (const float*)d_in[2];
    const float* enc_w2 = (const float*)d_in[3];
    const float* enc_b2 = (const float*)d_in[4];
    const float* dec_w1 = (const float*)d_in[5];
    const float* dec_b1 = (const float*)d_in[6];
    const float* dec_w2 = (const float*)d_in[7];
    const float* dec_b2 = (const float*)d_in[8];
    const float* cb = (const float*)d_in[9];

    char* ws = (char*)d_ws;
    size_t o = 0;
    float* accum = (float*)(ws + o); o += 256;
    unsigned short* enc_w1t = (unsigned short*)(ws + o); o += (size_t)NLEV * HID * NF * 2;  // [l][n][k]
    unsigned short* enc_w2t = (unsigned short*)(ws + o); o += (size_t)NLEV * VQD * HID * 2;
    unsigned short* dec_w1t = (unsigned short*)(ws + o); o += (size_t)NLEV * HID * VQD * 2;
    unsigned short* dec_w2t = (unsigned short*)(ws + o); o += (size_t)NLEV * NF * HID * 2;
    unsigned short* cbb = (unsigned short*)(ws + o); o += (size_t)NLEV * CBS * VQD * 2;
    float* cbn = (float*)(ws + o); o += (size_t)NLEV * CBS * 4;
    unsigned short* xb = (unsigned short*)(ws + o); o += (size_t)NLEV * NS * NF * 2;  // 128 MB; reused as h2b
    unsigned short* hb = (unsigned short*)(ws + o); o += (size_t)NLEV * NS * HID * 2; // 128 MB
    float* zf = (float*)(ws + o); o += (size_t)NLEV * NS * VQD * 4;                   // 32 MB
    unsigned short* zb = (unsigned short*)(ws + o); o += (size_t)NLEV * NS * VQD * 2; // 16 MB
    int* idxp = (int*)(ws + o); o += (size_t)NLEV * NS * 4;
    unsigned short* h2b = xb;  // alias: xb dead after batched enc1

    hipMemsetAsync(accum, 0, 8, stream);

    transpose_all<<<(2 * NLEV * NF * HID + 2 * NLEV * HID * VQD + 255) / 256, 256, 0, stream>>>(
        enc_w1, enc_w2, dec_w1, dec_w2, enc_w1t, enc_w2t, dec_w1t, dec_w2t);
    cb_prep<<<(NLEV * CBS + 255) / 256, 256, 0, stream>>>(cb, cbb, cbn);
    xconv<<<(int)(((long)NLEV * NS * (NF / 8) + 255) / 256), 256, 0, stream>>>(x, xb);

    dim3 gBig(NS / 128, HID / 128, NLEV);  // (256, 4, 4)
    dim3 gZ(NS / 128, 1, NLEV);
    dim3 gVQ(NS / 128, NLEV);

    // enc1: h = relu(xb @ enc_w1 + b1)
    gemm128<4, 1, 0, 0><<<gBig, 256, 0, stream>>>(
        xb, NF, (long)NS * NF, nullptr,
        enc_w1t, (long)HID * NF, enc_b1, HID,
        hb, nullptr, (long)NS * HID, nullptr, 0, 0, nullptr, HID, NF);
    // enc2: z = h @ enc_w2 + b2  (bf16 + f32 z; f32 used by commit on last level)
    gemm128<2, 0, 1, 0><<<gZ, 256, 0, stream>>>(
        hb, HID, (long)NS * HID, nullptr,
        enc_w2t, (long)VQD * HID, enc_b2, VQD,
        zb, zf, (long)NS * VQD, nullptr, 0, 0, nullptr, VQD, HID);
    // argmin over codebook
    vq_argmin<<<gVQ, 256, 0, stream>>>(zb, cbb, cbn, idxp);
    // commit SSE, last level only
    commit_k<<<NS / 256, 256, 0, stream>>>(idxp + (long)(NLEV - 1) * NS,
                                           cb + (long)(NLEV - 1) * CBS * VQD,
                                           zf + (long)(NLEV - 1) * NS * VQD, accum + 1);
    // dec1: h2 = relu(cb[idx] @ dec_w1 + b1d), gather fused into A staging
    gemm128<4, 1, 0, 1><<<gBig, 256, 0, stream>>>(
        cbb, 0, (long)CBS * VQD, idxp,
        dec_w1t, (long)HID * VQD, dec_b1, HID,
        h2b, nullptr, (long)NS * HID, nullptr, 0, 0, nullptr, HID, VQD);
    // dec2 + fused MSE: x_hat = h2 @ dec_w2 + b2d; accumulate sum((x_hat - x_l)^2)
    gemm128<4, 0, 2, 0><<<gBig, 256, 0, stream>>>(
        h2b, HID, (long)NS * HID, nullptr,
        dec_w2t, (long)NF * HID, dec_b2, NF,
        nullptr, nullptr, 0, x, (long)NLEV * NF, NF, accum, NF, HID);

    finalize_k<<<1, 1, 0, stream>>>(accum, (float*)d_out);
}